// Round 2
// baseline (87.423 us; speedup 1.0000x reference)
//
#include <hip/hip_runtime.h>
#include <hip/hip_fp16.h>

// MinEuclideanDistBlock: out[b,n] = min_w sum_c sqrt(max(||win||^2 + ||shp||^2 - 2*cross, 0))
// B=64, C=3, L=2048, N=256, S=64, W=1985.
// v3: occupancy 16->32 waves/CU. Grid 512 = 64b x 2 n-halves x 4 w-quarters;
//     per-block LDS 53.2 KB -> 2 blocks/CU; VGPR forced <=64 via 16w x 16n wave tile
//     (bfr resident = 24 VGPR). Partial mins merged with atomicMin on float-as-uint
//     (nonneg floats order as uints); out pre-set to 0x7f7f7f7f via hipMemsetAsync.
//     A-read bank skew: copy r at +4r u64 (=8r banks), stride 160 u64 (=0 mod 32 banks)
//     -> lane bank = 8r+4q+2s = perfect 4-per-bank-pair (b64 floor, zero conflicts).
//     wsq stored f32 (no cvt in inner loop, better accuracy than f16).

typedef float  v4f __attribute__((ext_vector_type(4)));
typedef short  v8s __attribute__((ext_vector_type(8)));
typedef unsigned short u16;
typedef unsigned int   u32;
typedef unsigned long long u64;

#define S_ 64
#define N_ 256
#define C_ 3
#define B_ 64
#define L_ 2048
#define W_ 1985
#define WQL 512            // windows per w-quarter block
#define NC 146             // u64 chunks staged per shifted copy (584 els >= 512+63)
#define CSTRIDE 160        // u64 stride per copy (incl. 4r skew headroom; 160*2 dwords == 0 mod 32)
#define THREADS 1024

__device__ __forceinline__ u16 f2bf(float f) {
    u32 u = __builtin_bit_cast(u32, f);
    return (u16)((u + 0x7FFFu + ((u >> 16) & 1u)) >> 16);
}
__device__ __forceinline__ float bf2f(u16 b) {
    return __builtin_bit_cast(float, ((u32)b) << 16);
}

__global__ __launch_bounds__(THREADS, 8)
void shapelet_min_kernel(const float* __restrict__ x,
                         const float* __restrict__ shp,
                         float* __restrict__ out)
{
    __shared__ u64   xls[C_ * 4 * CSTRIDE];  // 15360 B: 4 skewed shifted bf16 copies of -2*x
    __shared__ float wsq[C_][WQL];           // 6144 B : window sq-norms (f32)
    __shared__ u16   scratch[C_ * 64 * 72];  // 27648 B: shapelet tile (row stride 72 = 64+pad)
    __shared__ float red[16][64];            // 4096 B : cross-wave min reduction

    const int tid  = threadIdx.x;
    const int wave = tid >> 6;
    const int lane = tid & 63;
    const int m    = lane & 15;      // MFMA row/col within 16
    const int q    = lane >> 4;      // quad id 0..3
    const int ww   = wave & 3;       // w-group 0..3 (16 windows each per iter)
    const int wn   = wave >> 2;      // n-group 0..3 (16 shapelets each)
    const int blk  = blockIdx.x;
    const int wq   = blk & 3;
    const int nh   = (blk >> 2) & 1;
    const int b    = blk >> 3;
    const int w0   = wq << 9;                        // quarter base window
    const int wlen = min(WQL, W_ - w0);              // 512,512,512,449

    //=== Issue x global loads early (quarter [w0, w0+584) of each channel) ===
    const float* xb = x + (size_t)b * (C_ * L_);
    float xf[8];
    int xc = 0, xt = 0;
    bool xact = (tid < C_ * NC);                     // 438 active
    if (xact) {
        xc = tid / NC;
        xt = tid - xc * NC;
        int e = w0 + (xt << 2);
        if (e + 7 < L_) {
            v4f a0 = *(const v4f*)(xb + xc * L_ + e);
            v4f a1 = *(const v4f*)(xb + xc * L_ + e + 4);
            xf[0] = a0[0]; xf[1] = a0[1]; xf[2] = a0[2]; xf[3] = a0[3];
            xf[4] = a1[0]; xf[5] = a1[1]; xf[6] = a1[2]; xf[7] = a1[3];
        } else {
            #pragma unroll
            for (int i = 0; i < 8; ++i)
                xf[i] = (e + i < L_) ? xb[xc * L_ + e + i] : 0.f;
        }
    }

    //=== Stage shapelet tile for n-group g=0 (global loads overlap x-load latency) ===
    const int nbase = nh << 7;                       // 128-sized n-half
    #pragma unroll
    for (int k = 0; k < 3; ++k) {
        int idx = tid + k * THREADS;                 // 3072 float4-groups: (c, n, sq)
        int sq = idx & 15;
        int n  = (idx >> 4) & 63;
        int c  = idx >> 10;
        v4f v = *(const v4f*)(shp + ((size_t)(c * N_ + nbase + n) * S_ + (sq << 2)));
        u64 pk = (u64)f2bf(v[0]) | ((u64)f2bf(v[1]) << 16)
               | ((u64)f2bf(v[2]) << 32) | ((u64)f2bf(v[3]) << 48);
        *(u64*)(scratch + ((c * 64 + n) * 72 + (sq << 2))) = pk;
    }

    //=== Write 4 skewed shifted bf16 copies of -2*x (whole aligned u64 chunks) ===
    if (xact) {
        u16 w8[8];
        #pragma unroll
        for (int i = 0; i < 8; ++i) w8[i] = f2bf(-2.f * xf[i]);
        #pragma unroll
        for (int r = 0; r < 4; ++r) {                // copy r chunk t = elements 4t+r..4t+r+3
            u64 pk = (u64)w8[r] | ((u64)w8[r + 1] << 16)
                   | ((u64)w8[r + 2] << 32) | ((u64)w8[r + 3] << 48);
            xls[(xc * 4 + r) * CSTRIDE + 4 * r + xt] = pk;
        }
    }
    __syncthreads();

    //=== wsq: rolling sliding sum of squares from copy 0 (values -2x -> *0.25), f32 ===
    if (tid < 128 * C_) {                            // 384 units: (c, 4-window group)
        int c  = tid >> 7;
        int t0 = tid & 127;                          // window base = 4*t0
        const u64* cp0 = &xls[(c * 4) * CSTRIDE];
        u64 ch = cp0[t0];
        float h0 = bf2f((u16)ch),         h1 = bf2f((u16)(ch >> 16)),
              h2 = bf2f((u16)(ch >> 32)), h3 = bf2f((u16)(ch >> 48));
        float sq0 = h0 * h0, sq1 = h1 * h1, sq2 = h2 * h2;
        float s = sq0 + sq1 + sq2 + h3 * h3;
        #pragma unroll
        for (int kk = 1; kk < 16; ++kk) {
            u64 c2 = cp0[t0 + kk];
            float e0 = bf2f((u16)c2),         e1 = bf2f((u16)(c2 >> 16)),
                  e2 = bf2f((u16)(c2 >> 32)), e3 = bf2f((u16)(c2 >> 48));
            s += e0 * e0; s += e1 * e1; s += e2 * e2; s += e3 * e3;
        }
        u64 ct = cp0[t0 + 16];
        float t4 = bf2f((u16)ct), t5 = bf2f((u16)(ct >> 16)), t6 = bf2f((u16)(ct >> 32));
        float s0 = s;
        float s1 = s0 - sq0 + t4 * t4;
        float s2 = s1 - sq1 + t5 * t5;
        float s3 = s2 - sq2 + t6 * t6;
        v4f o = (v4f){0.25f * s0, 0.25f * s1, 0.25f * s2, 0.25f * s3};
        *(v4f*)&wsq[c][t0 << 2] = o;
    }

    const int r  = m & 3;
    const int sE = m >> 2;

    //=== Two n-groups of 64; per group: load B frags, 8 w-iters, reduce, atomicMin ===
    #pragma unroll 1
    for (int g = 0; g < 2; ++g) {
        // B fragments (24 VGPR) + shapelet norms; scratch holds group g (sync'd)
        v8s bfr[C_][2];
        float ssq[C_];
        #pragma unroll
        for (int c = 0; c < C_; ++c) {
            float sacc = 0.f;
            #pragma unroll
            for (int h = 0; h < 2; ++h) {
                v8s f = *(const v8s*)(scratch +
                         ((c * 64 + wn * 16 + m) * 72 + h * 32 + q * 8));
                bfr[c][h] = f;
                #pragma unroll
                for (int j = 0; j < 8; ++j) {
                    float e = bf2f((u16)f[j]);
                    sacc += e * e;
                }
            }
            sacc += __shfl_xor(sacc, 16);
            sacc += __shfl_xor(sacc, 32);
            ssq[c] = sacc;                           // per-lane n = wn*16 + m
        }
        __syncthreads();                             // wsq ready (g=0); red free (g=1)

        float minv = 1e30f;
        #pragma unroll 1
        for (int it = 0; it < 8; ++it) {
            const int wb = it * 64 + ww * 16;        // local window base for this wave
            if (wb >= wlen) continue;                // wave-uniform

            float sums[4] = {0.f, 0.f, 0.f, 0.f};
            #pragma unroll
            for (int c = 0; c < C_; ++c) {
                // A fragments: bank = 8r+4q+2s -> conflict-free b64 pairs
                const u64* cp = &xls[(c * 4 + r) * CSTRIDE + 4 * r];
                int T0 = (wb >> 2) + 2 * q + sE;
                union { u64 u[2]; v8s v; } a0, a1;
                a0.u[0] = cp[T0];     a0.u[1] = cp[T0 + 1];
                a1.u[0] = cp[T0 + 8]; a1.u[1] = cp[T0 + 9];

                // acc init = wsq(w) + ssq(n); MFMA adds -2*cross
                v4f wv = *(const v4f*)&wsq[c][wb + (q << 2)];
                v4f acc;
                #pragma unroll
                for (int gi = 0; gi < 4; ++gi) acc[gi] = wv[gi] + ssq[c];
                acc = __builtin_amdgcn_mfma_f32_16x16x32_bf16(a0.v, bfr[c][0], acc, 0, 0, 0);
                acc = __builtin_amdgcn_mfma_f32_16x16x32_bf16(a1.v, bfr[c][1], acc, 0, 0, 0);

                #pragma unroll
                for (int gi = 0; gi < 4; ++gi)
                    sums[gi] += __builtin_amdgcn_sqrtf(fmaxf(acc[gi], 0.f));
            }
            if (wb + 16 <= wlen) {
                #pragma unroll
                for (int gi = 0; gi < 4; ++gi) minv = fminf(minv, sums[gi]);
            } else {
                #pragma unroll
                for (int gi = 0; gi < 4; ++gi) {
                    bool ok = (wb + (q << 2) + gi) < wlen;
                    minv = fminf(minv, ok ? sums[gi] : 1e30f);
                }
            }
        }

        // quad reduce (same n across q), stash per-wave mins
        minv = fminf(minv, __shfl_xor(minv, 16));
        minv = fminf(minv, __shfl_xor(minv, 32));

        // overlap: stage next n-group's shapelets while finishing this group's output
        if (g == 0) {
            #pragma unroll
            for (int k = 0; k < 3; ++k) {
                int idx = tid + k * THREADS;
                int sq = idx & 15;
                int n  = (idx >> 4) & 63;
                int c  = idx >> 10;
                v4f v = *(const v4f*)(shp +
                        ((size_t)(c * N_ + nbase + 64 + n) * S_ + (sq << 2)));
                u64 pk = (u64)f2bf(v[0]) | ((u64)f2bf(v[1]) << 16)
                       | ((u64)f2bf(v[2]) << 32) | ((u64)f2bf(v[3]) << 48);
                *(u64*)(scratch + ((c * 64 + n) * 72 + (sq << 2))) = pk;
            }
        }
        if (lane < 16) red[wave][wn * 16 + lane] = minv;
        __syncthreads();

        if (tid < 64) {
            int tn = tid >> 4;                       // which wn owns this n
            float v = red[tn * 4 + 0][tid];
            v = fminf(v, red[tn * 4 + 1][tid]);
            v = fminf(v, red[tn * 4 + 2][tid]);
            v = fminf(v, red[tn * 4 + 3][tid]);
            // nonneg floats order as uints -> atomicMin merges w-quarter partials
            atomicMin((u32*)out + ((size_t)b * N_ + nbase + (g << 6) + tid),
                      __float_as_uint(v));
        }
        // next g: scratch re-read (bfr load) happens after the barrier below
        if (g == 0) __syncthreads();
    }
}

extern "C" void kernel_launch(void* const* d_in, const int* in_sizes, int n_in,
                              void* d_out, int out_size, void* d_ws, size_t ws_size,
                              hipStream_t stream) {
    const float* x   = (const float*)d_in[0];   // (64, 3, 2048) fp32
    const float* shp = (const float*)d_in[1];   // (3, 256, 64) fp32
    float* out       = (float*)d_out;           // (64, 1, 256) fp32
    // init output to +huge (0x7f7f7f7f ~ 3.39e38) for atomicMin merging
    hipMemsetAsync(d_out, 0x7f, (size_t)B_ * N_ * sizeof(float), stream);
    hipLaunchKernelGGL(shapelet_min_kernel, dim3(512), dim3(THREADS), 0, stream,
                       x, shp, (float*)d_out);
}

// Round 3
// 85.138 us; speedup vs baseline: 1.0268x; 1.0268x over previous
//
#include <hip/hip_runtime.h>
#include <hip/hip_fp16.h>

// MinEuclideanDistBlock: out[b,n] = min_w sum_c sqrt(max(||win||^2 + ||shp||^2 - 2*cross, 0))
// B=64, C=3, L=2048, N=256, S=64, W=1985.
// v4: LDS-traffic fix. Wave tile 16w x 32n (nt=2, bfr=48 VGPR resident) halves A-read
//     b128s per MFMA vs v3. 512-thread blocks (8 waves: 4 w-groups x 2 n-groups),
//     grid 512 = 64b x 2 n-halves x 4 w-quarters -> 2 blocks/CU, 16 waves/CU at
//     VGPR<=128 (__launch_bounds__(512,4)). Two independent blocks/CU overlap their
//     staging phases. All v3 machinery kept: skewed conflict-free shifted copies,
//     f32 wsq, atomicMin merge (nonneg float-as-uint), memset 0x7f init.

typedef float  v4f __attribute__((ext_vector_type(4)));
typedef short  v8s __attribute__((ext_vector_type(8)));
typedef unsigned short u16;
typedef unsigned int   u32;
typedef unsigned long long u64;

#define S_ 64
#define N_ 256
#define C_ 3
#define B_ 64
#define L_ 2048
#define W_ 1985
#define WQL 512            // windows per w-quarter block
#define NC 146             // u64 chunks staged per shifted copy (584 els >= 512+63)
#define CSTRIDE 160        // u64 stride per copy (incl. 4r skew headroom; 320 dwords == 0 mod 32)
#define THREADS 512

__device__ __forceinline__ u16 f2bf(float f) {
    u32 u = __builtin_bit_cast(u32, f);
    return (u16)((u + 0x7FFFu + ((u >> 16) & 1u)) >> 16);
}
__device__ __forceinline__ float bf2f(u16 b) {
    return __builtin_bit_cast(float, ((u32)b) << 16);
}

__global__ __launch_bounds__(THREADS, 4)
void shapelet_min_kernel(const float* __restrict__ x,
                         const float* __restrict__ shp,
                         float* __restrict__ out)
{
    __shared__ u64   xls[C_ * 4 * CSTRIDE];  // 15360 B: 4 skewed shifted bf16 copies of -2*x
    __shared__ float wsq[C_][WQL];           // 6144 B : window sq-norms (f32)
    __shared__ u16   scratch[C_ * 64 * 72];  // 27648 B: shapelet tile (row stride 72 = 64+pad)
    __shared__ float red[8][64];             // 2048 B : cross-wave min reduction

    const int tid  = threadIdx.x;
    const int wave = tid >> 6;
    const int lane = tid & 63;
    const int m    = lane & 15;      // MFMA row/col within 16
    const int q    = lane >> 4;      // quad id 0..3
    const int ww   = wave & 3;       // w-group 0..3 (16 windows each per iter)
    const int wn   = wave >> 2;      // n-group 0..1 (32 shapelets each)
    const int blk  = blockIdx.x;
    const int wq   = blk & 3;
    const int nh   = (blk >> 2) & 1;
    const int b    = blk >> 3;
    const int w0   = wq << 9;                        // quarter base window
    const int wlen = min(WQL, W_ - w0);              // 512,512,512,449

    //=== Issue x global loads early (quarter [w0, w0+584) of each channel) ===
    const float* xb = x + (size_t)b * (C_ * L_);
    float xf[8];
    int xc = 0, xt = 0;
    bool xact = (tid < C_ * NC);                     // 438 active
    if (xact) {
        xc = tid / NC;
        xt = tid - xc * NC;
        int e = w0 + (xt << 2);
        if (e + 7 < L_) {
            v4f a0 = *(const v4f*)(xb + xc * L_ + e);
            v4f a1 = *(const v4f*)(xb + xc * L_ + e + 4);
            xf[0] = a0[0]; xf[1] = a0[1]; xf[2] = a0[2]; xf[3] = a0[3];
            xf[4] = a1[0]; xf[5] = a1[1]; xf[6] = a1[2]; xf[7] = a1[3];
        } else {
            #pragma unroll
            for (int i = 0; i < 8; ++i)
                xf[i] = (e + i < L_) ? xb[xc * L_ + e + i] : 0.f;
        }
    }

    //=== Stage shapelet tile for n-group g=0 (overlaps x-load latency) ===
    const int nbase = nh << 7;                       // 128-sized n-half
    #pragma unroll
    for (int k = 0; k < 6; ++k) {
        int idx = tid + k * THREADS;                 // 3072 float4-groups: (c, n, sq)
        int sq = idx & 15;
        int n  = (idx >> 4) & 63;
        int c  = idx >> 10;
        v4f v = *(const v4f*)(shp + ((size_t)(c * N_ + nbase + n) * S_ + (sq << 2)));
        u64 pk = (u64)f2bf(v[0]) | ((u64)f2bf(v[1]) << 16)
               | ((u64)f2bf(v[2]) << 32) | ((u64)f2bf(v[3]) << 48);
        *(u64*)(scratch + ((c * 64 + n) * 72 + (sq << 2))) = pk;
    }

    //=== Write 4 skewed shifted bf16 copies of -2*x (whole aligned u64 chunks) ===
    if (xact) {
        u16 w8[8];
        #pragma unroll
        for (int i = 0; i < 8; ++i) w8[i] = f2bf(-2.f * xf[i]);
        #pragma unroll
        for (int r = 0; r < 4; ++r) {                // copy r chunk t = elements 4t+r..4t+r+3
            u64 pk = (u64)w8[r] | ((u64)w8[r + 1] << 16)
                   | ((u64)w8[r + 2] << 32) | ((u64)w8[r + 3] << 48);
            xls[(xc * 4 + r) * CSTRIDE + 4 * r + xt] = pk;
        }
    }
    __syncthreads();

    //=== wsq: rolling sliding sum of squares from copy 0 (values -2x -> *0.25), f32 ===
    if (tid < 128 * C_) {                            // 384 units: (c, 4-window group)
        int c  = tid >> 7;
        int t0 = tid & 127;                          // window base = 4*t0
        const u64* cp0 = &xls[(c * 4) * CSTRIDE];
        u64 ch = cp0[t0];
        float h0 = bf2f((u16)ch),         h1 = bf2f((u16)(ch >> 16)),
              h2 = bf2f((u16)(ch >> 32)), h3 = bf2f((u16)(ch >> 48));
        float sq0 = h0 * h0, sq1 = h1 * h1, sq2 = h2 * h2;
        float s = sq0 + sq1 + sq2 + h3 * h3;
        #pragma unroll
        for (int kk = 1; kk < 16; ++kk) {
            u64 c2 = cp0[t0 + kk];
            float e0 = bf2f((u16)c2),         e1 = bf2f((u16)(c2 >> 16)),
                  e2 = bf2f((u16)(c2 >> 32)), e3 = bf2f((u16)(c2 >> 48));
            s += e0 * e0; s += e1 * e1; s += e2 * e2; s += e3 * e3;
        }
        u64 ct = cp0[t0 + 16];
        float t4 = bf2f((u16)ct), t5 = bf2f((u16)(ct >> 16)), t6 = bf2f((u16)(ct >> 32));
        float s0 = s;
        float s1 = s0 - sq0 + t4 * t4;
        float s2 = s1 - sq1 + t5 * t5;
        float s3 = s2 - sq2 + t6 * t6;
        v4f o = (v4f){0.25f * s0, 0.25f * s1, 0.25f * s2, 0.25f * s3};
        *(v4f*)&wsq[c][t0 << 2] = o;
    }

    const int r  = m & 3;
    const int sE = m >> 2;

    //=== Two n-groups of 64; per group: B frags (nt=2), 8 w-iters, reduce, atomicMin ===
    #pragma unroll 1
    for (int g = 0; g < 2; ++g) {
        // B fragments (48 VGPR) + shapelet norms; scratch holds group g
        v8s bfr[C_][2][2];
        float ssq[C_][2];
        #pragma unroll
        for (int c = 0; c < C_; ++c) {
            #pragma unroll
            for (int nt = 0; nt < 2; ++nt) {
                float sacc = 0.f;
                #pragma unroll
                for (int h = 0; h < 2; ++h) {
                    v8s f = *(const v8s*)(scratch +
                             ((c * 64 + wn * 32 + nt * 16 + m) * 72 + h * 32 + q * 8));
                    bfr[c][nt][h] = f;
                    #pragma unroll
                    for (int j = 0; j < 8; ++j) {
                        float e = bf2f((u16)f[j]);
                        sacc += e * e;
                    }
                }
                sacc += __shfl_xor(sacc, 16);
                sacc += __shfl_xor(sacc, 32);
                ssq[c][nt] = sacc;                   // per-lane n = wn*32 + nt*16 + m
            }
        }
        __syncthreads();                             // wsq ready (g=0); red free (g=1)

        float minv[2] = {1e30f, 1e30f};
        #pragma unroll 1
        for (int it = 0; it < 8; ++it) {
            const int wb = it * 64 + ww * 16;        // local window base for this wave
            if (wb >= wlen) continue;                // wave-uniform

            float sums[2][4];
            #pragma unroll
            for (int nt = 0; nt < 2; ++nt)
                #pragma unroll
                for (int gi = 0; gi < 4; ++gi) sums[nt][gi] = 0.f;

            #pragma unroll
            for (int c = 0; c < C_; ++c) {
                // A fragments: bank = 8r+4q+2s -> conflict-free b64 pairs
                const u64* cp = &xls[(c * 4 + r) * CSTRIDE + 4 * r];
                int T0 = (wb >> 2) + 2 * q + sE;
                union { u64 u[2]; v8s v; } a0, a1;
                a0.u[0] = cp[T0];     a0.u[1] = cp[T0 + 1];
                a1.u[0] = cp[T0 + 8]; a1.u[1] = cp[T0 + 9];

                // acc init = wsq(w) + ssq(n); MFMA adds -2*cross (A pre-scaled)
                v4f wv = *(const v4f*)&wsq[c][wb + (q << 2)];
                v4f acc[2];
                #pragma unroll
                for (int nt = 0; nt < 2; ++nt)
                    #pragma unroll
                    for (int gi = 0; gi < 4; ++gi)
                        acc[nt][gi] = wv[gi] + ssq[c][nt];
                #pragma unroll
                for (int nt = 0; nt < 2; ++nt) {
                    acc[nt] = __builtin_amdgcn_mfma_f32_16x16x32_bf16(a0.v, bfr[c][nt][0], acc[nt], 0, 0, 0);
                    acc[nt] = __builtin_amdgcn_mfma_f32_16x16x32_bf16(a1.v, bfr[c][nt][1], acc[nt], 0, 0, 0);
                }
                #pragma unroll
                for (int nt = 0; nt < 2; ++nt)
                    #pragma unroll
                    for (int gi = 0; gi < 4; ++gi)
                        sums[nt][gi] += __builtin_amdgcn_sqrtf(fmaxf(acc[nt][gi], 0.f));
            }
            if (wb + 16 <= wlen) {
                #pragma unroll
                for (int nt = 0; nt < 2; ++nt)
                    #pragma unroll
                    for (int gi = 0; gi < 4; ++gi)
                        minv[nt] = fminf(minv[nt], sums[nt][gi]);
            } else {
                #pragma unroll
                for (int gi = 0; gi < 4; ++gi) {
                    bool ok = (wb + (q << 2) + gi) < wlen;
                    #pragma unroll
                    for (int nt = 0; nt < 2; ++nt)
                        minv[nt] = fminf(minv[nt], ok ? sums[nt][gi] : 1e30f);
                }
            }
        }

        // quad reduce (same n across q)
        #pragma unroll
        for (int nt = 0; nt < 2; ++nt) {
            minv[nt] = fminf(minv[nt], __shfl_xor(minv[nt], 16));
            minv[nt] = fminf(minv[nt], __shfl_xor(minv[nt], 32));
        }

        // overlap: stage next n-group's shapelets while finishing this group's output
        if (g == 0) {
            #pragma unroll
            for (int k = 0; k < 6; ++k) {
                int idx = tid + k * THREADS;
                int sq = idx & 15;
                int n  = (idx >> 4) & 63;
                int c  = idx >> 10;
                v4f v = *(const v4f*)(shp +
                        ((size_t)(c * N_ + nbase + 64 + n) * S_ + (sq << 2)));
                u64 pk = (u64)f2bf(v[0]) | ((u64)f2bf(v[1]) << 16)
                       | ((u64)f2bf(v[2]) << 32) | ((u64)f2bf(v[3]) << 48);
                *(u64*)(scratch + ((c * 64 + n) * 72 + (sq << 2))) = pk;
            }
        }
        if (lane < 16) {
            red[wave][wn * 32 + lane]      = minv[0];
            red[wave][wn * 32 + 16 + lane] = minv[1];
        }
        __syncthreads();

        if (tid < 64) {
            int tn = tid >> 5;                       // which wn owns this n (waves tn*4..tn*4+3... wave = wn*4+ww)
            float v = red[tn * 4 + 0][tid];
            v = fminf(v, red[tn * 4 + 1][tid]);
            v = fminf(v, red[tn * 4 + 2][tid]);
            v = fminf(v, red[tn * 4 + 3][tid]);
            // nonneg floats order as uints -> atomicMin merges w-quarter partials
            atomicMin((u32*)out + ((size_t)b * N_ + nbase + (g << 6) + tid),
                      __float_as_uint(v));
        }
        // next g: scratch re-read (bfr load) happens after this barrier
        if (g == 0) __syncthreads();
    }
}

extern "C" void kernel_launch(void* const* d_in, const int* in_sizes, int n_in,
                              void* d_out, int out_size, void* d_ws, size_t ws_size,
                              hipStream_t stream) {
    const float* x   = (const float*)d_in[0];   // (64, 3, 2048) fp32
    const float* shp = (const float*)d_in[1];   // (3, 256, 64) fp32
    float* out       = (float*)d_out;           // (64, 1, 256) fp32
    // init output to +huge (0x7f7f7f7f ~ 3.39e38) for atomicMin merging
    hipMemsetAsync(d_out, 0x7f, (size_t)B_ * N_ * sizeof(float), stream);
    hipLaunchKernelGGL(shapelet_min_kernel, dim3(512), dim3(THREADS), 0, stream,
                       x, shp, (float*)d_out);
}